// Round 1
// baseline (815.422 us; speedup 1.0000x reference)
//
#include <hip/hip_runtime.h>
#include <hip/hip_bf16.h>

#define N_HID 128

// ---------------- preprocessing kernels ----------------

__global__ void k_init_deg(int* deg, int n) {
    int i = blockIdx.x * 256 + threadIdx.x;
    if (i < n) deg[i] = 1;  // self-loop
}

__global__ void k_hist(const int* __restrict__ dst, int E, int* deg) {
    int i = blockIdx.x * 256 + threadIdx.x;
    if (i < E) atomicAdd(&deg[dst[i]], 1);
}

__global__ void k_dinv(const int* __restrict__ deg, float* __restrict__ dinv, int n) {
    int i = blockIdx.x * 256 + threadIdx.x;
    if (i < n) dinv[i] = rsqrtf((float)deg[i]);
}

// per-block inclusive scan of deg -> rptr holds per-block exclusive partials
__global__ void k_scan1(const int* __restrict__ deg, int* __restrict__ rptr,
                        int* __restrict__ bsums, int n) {
    __shared__ int s[256];
    int t = threadIdx.x;
    int i = blockIdx.x * 256 + t;
    int v = (i < n) ? deg[i] : 0;
    s[t] = v;
    __syncthreads();
    for (int off = 1; off < 256; off <<= 1) {
        int y = (t >= off) ? s[t - off] : 0;
        __syncthreads();
        s[t] += y;
        __syncthreads();
    }
    if (i < n) rptr[i] = s[t] - v;      // exclusive within block
    if (t == 255) bsums[blockIdx.x] = s[255];
}

__global__ void k_scan2(int* bsums, int nb) {
    __shared__ int s[512];
    int t = threadIdx.x;
    int v = (t < nb) ? bsums[t] : 0;
    s[t] = v;
    __syncthreads();
    for (int off = 1; off < 512; off <<= 1) {
        int y = (t >= off) ? s[t - off] : 0;
        __syncthreads();
        s[t] += y;
        __syncthreads();
    }
    if (t < nb) bsums[t] = s[t] - v;    // exclusive block offsets
}

__global__ void k_scan3(int* __restrict__ rptr, const int* __restrict__ bsums,
                        int* __restrict__ cursor, int n, int total) {
    int i = blockIdx.x * 256 + threadIdx.x;
    if (i < n) {
        int v = rptr[i] + bsums[blockIdx.x];
        rptr[i] = v;
        cursor[i] = v;
    }
    if (i == 0) rptr[n] = total;
}

__global__ void k_fill(const int* __restrict__ src, const int* __restrict__ dst,
                       int E, int n, int* cursor, int* __restrict__ colx) {
    int i = blockIdx.x * 256 + threadIdx.x;
    int s, d;
    if (i < E)          { s = src[i]; d = dst[i]; }
    else if (i < E + n) { s = i - E;  d = i - E; }
    else return;
    int pos = atomicAdd(&cursor[d], 1);
    colx[pos] = s;
}

// ---------------- dense GEMM: C[M x 128] = A[M x 128] @ W[128 x 128] ----------------
// 128x128 tile per block, 256 threads, 8x8 register micro-tile, K chunked by 32.

__global__ __launch_bounds__(256) void k_gemm(const float* __restrict__ A,
                                              const float* __restrict__ W,
                                              float* __restrict__ C, int M) {
    __shared__ float As[32][132];   // transposed chunk: As[k][row], padded
    __shared__ float Ws[32][128];   // Ws[k][col]
    int tid = threadIdx.x;
    int tx = tid & 15;              // 16 col-groups of 8
    int ty = tid >> 4;              // 16 row-groups of 8
    int bm = blockIdx.x * 128;
    float acc[8][8] = {};

    for (int k0 = 0; k0 < 128; k0 += 32) {
        // stage A chunk (128 rows x 32 k), transposed into As
        #pragma unroll
        for (int it = 0; it < 4; ++it) {
            int idx = it * 256 + tid;       // 0..1023
            int row = idx >> 3;
            int kq  = idx & 7;
            int grow = bm + row;
            float4 v = make_float4(0.f, 0.f, 0.f, 0.f);
            if (grow < M) v = *(const float4*)(A + (size_t)grow * 128 + k0 + kq * 4);
            As[kq * 4 + 0][row] = v.x;
            As[kq * 4 + 1][row] = v.y;
            As[kq * 4 + 2][row] = v.z;
            As[kq * 4 + 3][row] = v.w;
        }
        // stage W chunk (32 k x 128 cols)
        #pragma unroll
        for (int it = 0; it < 4; ++it) {
            int idx = it * 256 + tid;
            int kk = idx >> 5;
            int q  = idx & 31;
            *(float4*)&Ws[kk][q * 4] = *(const float4*)(W + (size_t)(k0 + kk) * 128 + q * 4);
        }
        __syncthreads();
        #pragma unroll
        for (int kk = 0; kk < 32; ++kk) {
            float a[8], w[8];
            *(float4*)&a[0] = *(const float4*)&As[kk][ty * 8];
            *(float4*)&a[4] = *(const float4*)&As[kk][ty * 8 + 4];
            *(float4*)&w[0] = *(const float4*)&Ws[kk][tx * 8];
            *(float4*)&w[4] = *(const float4*)&Ws[kk][tx * 8 + 4];
            #pragma unroll
            for (int i = 0; i < 8; ++i)
                #pragma unroll
                for (int j = 0; j < 8; ++j)
                    acc[i][j] = fmaf(a[i], w[j], acc[i][j]);
        }
        __syncthreads();
    }
    #pragma unroll
    for (int i = 0; i < 8; ++i) {
        int grow = bm + ty * 8 + i;
        if (grow < M) {
            *(float4*)(C + (size_t)grow * 128 + tx * 8)     = *(float4*)&acc[i][0];
            *(float4*)(C + (size_t)grow * 128 + tx * 8 + 4) = *(float4*)&acc[i][4];
        }
    }
}

// ---------------- SpMM aggregate: out[i] = act(dinv[i]*sum_j dinv[j]*H[j] + b) ----------------
// one wave per node, lane covers 2 columns (float2)

__global__ __launch_bounds__(256) void k_spmm(const float* __restrict__ H,
                                              const int* __restrict__ colx,
                                              const int* __restrict__ rptr,
                                              const float* __restrict__ dinv,
                                              const float* __restrict__ bias,
                                              float* __restrict__ out,
                                              int n, int do_relu) {
    int wave = blockIdx.x * 4 + (threadIdx.x >> 6);
    int lane = threadIdx.x & 63;
    if (wave >= n) return;
    int e0 = rptr[wave];
    int e1 = rptr[wave + 1];
    float ax = 0.f, ay = 0.f;
    int e = e0;
    for (; e + 1 < e1; e += 2) {
        int s0 = colx[e];
        int s1 = colx[e + 1];
        float w0 = dinv[s0];
        float w1 = dinv[s1];
        float2 h0 = *(const float2*)(H + (size_t)s0 * 128 + lane * 2);
        float2 h1 = *(const float2*)(H + (size_t)s1 * 128 + lane * 2);
        ax = fmaf(w0, h0.x, ax); ay = fmaf(w0, h0.y, ay);
        ax = fmaf(w1, h1.x, ax); ay = fmaf(w1, h1.y, ay);
    }
    if (e < e1) {
        int s0 = colx[e];
        float w0 = dinv[s0];
        float2 h0 = *(const float2*)(H + (size_t)s0 * 128 + lane * 2);
        ax = fmaf(w0, h0.x, ax); ay = fmaf(w0, h0.y, ay);
    }
    float di = dinv[wave];
    float2 b = *(const float2*)(bias + lane * 2);
    float ox = fmaf(di, ax, b.x);
    float oy = fmaf(di, ay, b.y);
    if (do_relu) { ox = fmaxf(ox, 0.f); oy = fmaxf(oy, 0.f); }
    *(float2*)(out + (size_t)wave * 128 + lane * 2) = make_float2(ox, oy);
}

// ---------------- host ----------------

extern "C" void kernel_launch(void* const* d_in, const int* in_sizes, int n_in,
                              void* d_out, int out_size, void* d_ws, size_t ws_size,
                              hipStream_t stream) {
    const float* x  = (const float*)d_in[0];
    const int*   ei = (const int*)d_in[1];
    const float* W1 = (const float*)d_in[2];
    const float* b1 = (const float*)d_in[3];
    const float* W2 = (const float*)d_in[4];
    const float* b2 = (const float*)d_in[5];
    const float* W3 = (const float*)d_in[6];
    const float* b3 = (const float*)d_in[7];
    float* out = (float*)d_out;

    const int n = in_sizes[0] / N_HID;       // 100000
    const int E = in_sizes[1] / 2;           // 1600000
    const int total = E + n;

    const int* src = ei;
    const int* dst = ei + E;

    // ws layout
    size_t off = 0;
    auto alloc = [&](size_t bytes) {
        size_t o = off;
        off += (bytes + 255) & ~(size_t)255;
        return (char*)d_ws + o;
    };
    int*   deg    = (int*)  alloc((size_t)n * 4);
    float* dinv   = (float*)alloc((size_t)n * 4);
    int*   rptr   = (int*)  alloc((size_t)(n + 1) * 4);
    int*   cursor = (int*)  alloc((size_t)n * 4);
    int*   bsums  = (int*)  alloc(4096);
    int*   colx   = (int*)  alloc((size_t)total * 4);
    float* HH     = (float*)alloc((size_t)n * N_HID * 4);
    (void)ws_size;

    int nb  = (n + 255) / 256;               // 391
    int ebk = (E + 255) / 256;
    int tbk = (total + 255) / 256;

    k_init_deg<<<nb, 256, 0, stream>>>(deg, n);
    k_hist<<<ebk, 256, 0, stream>>>(dst, E, deg);
    k_dinv<<<nb, 256, 0, stream>>>(deg, dinv, n);
    k_scan1<<<nb, 256, 0, stream>>>(deg, rptr, bsums, n);
    k_scan2<<<1, 512, 0, stream>>>(bsums, nb);
    k_scan3<<<nb, 256, 0, stream>>>(rptr, bsums, cursor, n, total);
    k_fill<<<tbk, 256, 0, stream>>>(src, dst, E, n, cursor, colx);

    int gblk = (n + 127) / 128;              // GEMM blocks
    int sblk = (n + 3) / 4;                  // SpMM blocks (4 waves/block)

    // layer 1: H = x @ W1 ; out = relu(agg(H) + b1)
    k_gemm<<<gblk, 256, 0, stream>>>(x, W1, HH, n);
    k_spmm<<<sblk, 256, 0, stream>>>(HH, colx, rptr, dinv, b1, out, n, 1);
    // layer 2
    k_gemm<<<gblk, 256, 0, stream>>>(out, W2, HH, n);
    k_spmm<<<sblk, 256, 0, stream>>>(HH, colx, rptr, dinv, b2, out, n, 1);
    // layer 3 (no relu)
    k_gemm<<<gblk, 256, 0, stream>>>(out, W3, HH, n);
    k_spmm<<<sblk, 256, 0, stream>>>(HH, colx, rptr, dinv, b3, out, n, 0);
}

// Round 2
// 730.665 us; speedup vs baseline: 1.1160x; 1.1160x over previous
//
#include <hip/hip_runtime.h>
#include <hip/hip_bf16.h>

#define N_HID 128

// ---------------- preprocessing kernels ----------------

__global__ void k_init_deg(int* deg, int n) {
    int i = blockIdx.x * 256 + threadIdx.x;
    if (i < n) deg[i] = 1;  // self-loop
}

__global__ void k_hist(const int* __restrict__ dst, int E, int* deg) {
    int i = blockIdx.x * 256 + threadIdx.x;
    if (i < E) atomicAdd(&deg[dst[i]], 1);
}

__global__ void k_dinv(const int* __restrict__ deg, float* __restrict__ dinv, int n) {
    int i = blockIdx.x * 256 + threadIdx.x;
    if (i < n) dinv[i] = rsqrtf((float)deg[i]);
}

// scan of PADDED degree (rounded up to multiple of 4)
__global__ void k_scan1(const int* __restrict__ deg, int* __restrict__ rptr,
                        int* __restrict__ bsums, int n) {
    __shared__ int s[256];
    int t = threadIdx.x;
    int i = blockIdx.x * 256 + t;
    int v = (i < n) ? ((deg[i] + 3) & ~3) : 0;
    s[t] = v;
    __syncthreads();
    for (int off = 1; off < 256; off <<= 1) {
        int y = (t >= off) ? s[t - off] : 0;
        __syncthreads();
        s[t] += y;
        __syncthreads();
    }
    if (i < n) rptr[i] = s[t] - v;      // exclusive within block
    if (t == 255) bsums[blockIdx.x] = s[255];
}

__global__ void k_scan2(int* bsums, int nb) {
    __shared__ int s[512];
    int t = threadIdx.x;
    int v = (t < nb) ? bsums[t] : 0;
    s[t] = v;
    __syncthreads();
    for (int off = 1; off < 512; off <<= 1) {
        int y = (t >= off) ? s[t - off] : 0;
        __syncthreads();
        s[t] += y;
        __syncthreads();
    }
    if (t < nb) bsums[t] = s[t] - v;    // exclusive block offsets
}

__global__ void k_scan3(int* __restrict__ rptr, const int* __restrict__ bsums,
                        const int* __restrict__ deg,
                        int* __restrict__ cursor, int n) {
    int i = blockIdx.x * 256 + threadIdx.x;
    if (i < n) {
        int v = rptr[i] + bsums[blockIdx.x];
        rptr[i] = v;
        cursor[i] = v;
        if (i == n - 1) rptr[n] = v + ((deg[i] + 3) & ~3);
    }
}

__global__ void k_fill(const int* __restrict__ src, const int* __restrict__ dst,
                       int E, int n, int* cursor, int* __restrict__ colx) {
    int i = blockIdx.x * 256 + threadIdx.x;
    int s, d;
    if (i < E)          { s = src[i]; d = dst[i]; }
    else if (i < E + n) { s = i - E;  d = i - E; }
    else return;
    int pos = atomicAdd(&cursor[d], 1);
    colx[pos] = s;
}

// pad each CSR row to its rounded length with dummy node n (zero row in Hs)
__global__ void k_pad(const int* __restrict__ rptr, const int* __restrict__ deg,
                      int* __restrict__ colx, int n) {
    int i = blockIdx.x * 256 + threadIdx.x;
    if (i >= n) return;
    int s = rptr[i] + deg[i];
    int e = rptr[i + 1];
    for (int p = s; p < e; ++p) colx[p] = n;
}

__global__ void k_zero_row(float* Hs, int n) {
    Hs[(size_t)n * N_HID + threadIdx.x] = 0.f;
}

// ---------------- dense GEMM: Hs[M x 128] = scale[.] * (A[M x 128] @ W[128 x 128]) --------
// 128x128 tile per block, 256 threads, 8x8 register micro-tile, K chunked by 32.
// Ws repacked [kk][h][tx][4] so inner-loop reads are 256B-contiguous (no 4-way conflict).

__global__ __launch_bounds__(256) void k_gemm(const float* __restrict__ A,
                                              const float* __restrict__ W,
                                              const float* __restrict__ scale,
                                              float* __restrict__ C, int M) {
    __shared__ float As[32][132];    // transposed chunk: As[k][row], padded
    __shared__ float Ws[32 * 128];   // repacked: [kk][h(2)][tx(16)][j(4)]
    int tid = threadIdx.x;
    int tx = tid & 15;               // 16 col-groups of 8
    int ty = tid >> 4;               // 16 row-groups of 8
    int bm = blockIdx.x * 128;
    float acc[8][8] = {};

    for (int k0 = 0; k0 < 128; k0 += 32) {
        // stage A chunk (128 rows x 32 k), transposed into As
        #pragma unroll
        for (int it = 0; it < 4; ++it) {
            int idx = it * 256 + tid;       // 0..1023
            int row = idx >> 3;
            int kq  = idx & 7;
            int grow = bm + row;
            float4 v = make_float4(0.f, 0.f, 0.f, 0.f);
            if (grow < M) v = *(const float4*)(A + (size_t)grow * 128 + k0 + kq * 4);
            As[kq * 4 + 0][row] = v.x;
            As[kq * 4 + 1][row] = v.y;
            As[kq * 4 + 2][row] = v.z;
            As[kq * 4 + 3][row] = v.w;
        }
        // stage W chunk (32 k x 128 cols), repacked
        #pragma unroll
        for (int it = 0; it < 4; ++it) {
            int idx = it * 256 + tid;
            int kk = idx >> 5;
            int q  = idx & 31;               // col block q -> col q*4
            float4 v = *(const float4*)(W + (size_t)(k0 + kk) * 128 + q * 4);
            *(float4*)&Ws[kk * 128 + ((q & 1) << 6) + ((q >> 1) << 2)] = v;
        }
        __syncthreads();
        #pragma unroll
        for (int kk = 0; kk < 32; ++kk) {
            float a[8], w[8];
            *(float4*)&a[0] = *(const float4*)&As[kk][ty * 8];
            *(float4*)&a[4] = *(const float4*)&As[kk][ty * 8 + 4];
            *(float4*)&w[0] = *(const float4*)&Ws[kk * 128 + tx * 4];
            *(float4*)&w[4] = *(const float4*)&Ws[kk * 128 + 64 + tx * 4];
            #pragma unroll
            for (int i = 0; i < 8; ++i)
                #pragma unroll
                for (int j = 0; j < 8; ++j)
                    acc[i][j] = fmaf(a[i], w[j], acc[i][j]);
        }
        __syncthreads();
    }
    #pragma unroll
    for (int i = 0; i < 8; ++i) {
        int grow = bm + ty * 8 + i;
        if (grow < M) {
            float di = scale[grow];
            float4 o0, o1;
            o0.x = acc[i][0] * di; o0.y = acc[i][1] * di;
            o0.z = acc[i][2] * di; o0.w = acc[i][3] * di;
            o1.x = acc[i][4] * di; o1.y = acc[i][5] * di;
            o1.z = acc[i][6] * di; o1.w = acc[i][7] * di;
            *(float4*)(C + (size_t)grow * 128 + tx * 8)     = o0;
            *(float4*)(C + (size_t)grow * 128 + tx * 8 + 4) = o1;
        }
    }
}

// ---------------- SpMM aggregate: out[i] = act(dinv[i]*sum_j Hs[j] + b) ----------------
// Hs is pre-scaled by dinv[src]. Half-wave (32 lanes) per node, float4 per lane.
// CSR rows padded to multiples of 4 -> clean int4 + 4x float4 loads per iter.

__global__ __launch_bounds__(256) void k_spmm(const float* __restrict__ Hs,
                                              const int* __restrict__ colx,
                                              const int* __restrict__ rptr,
                                              const float* __restrict__ dinv,
                                              const float* __restrict__ bias,
                                              float* __restrict__ out,
                                              int n, int do_relu) {
    int node = blockIdx.x * 8 + (threadIdx.x >> 5);
    int lane = threadIdx.x & 31;
    if (node >= n) return;
    int e  = rptr[node];
    int e1 = rptr[node + 1];
    const int c = lane * 4;
    float4 acc = make_float4(0.f, 0.f, 0.f, 0.f);
    #pragma unroll 2
    for (; e < e1; e += 4) {
        int4 s = *(const int4*)(colx + e);
        float4 h0 = *(const float4*)(Hs + (size_t)s.x * 128 + c);
        float4 h1 = *(const float4*)(Hs + (size_t)s.y * 128 + c);
        float4 h2 = *(const float4*)(Hs + (size_t)s.z * 128 + c);
        float4 h3 = *(const float4*)(Hs + (size_t)s.w * 128 + c);
        acc.x += (h0.x + h1.x) + (h2.x + h3.x);
        acc.y += (h0.y + h1.y) + (h2.y + h3.y);
        acc.z += (h0.z + h1.z) + (h2.z + h3.z);
        acc.w += (h0.w + h1.w) + (h2.w + h3.w);
    }
    float di = dinv[node];
    float4 b = *(const float4*)(bias + c);
    float4 o;
    o.x = fmaf(di, acc.x, b.x);
    o.y = fmaf(di, acc.y, b.y);
    o.z = fmaf(di, acc.z, b.z);
    o.w = fmaf(di, acc.w, b.w);
    if (do_relu) {
        o.x = fmaxf(o.x, 0.f); o.y = fmaxf(o.y, 0.f);
        o.z = fmaxf(o.z, 0.f); o.w = fmaxf(o.w, 0.f);
    }
    *(float4*)(out + (size_t)node * 128 + c) = o;
}

// ---------------- host ----------------

extern "C" void kernel_launch(void* const* d_in, const int* in_sizes, int n_in,
                              void* d_out, int out_size, void* d_ws, size_t ws_size,
                              hipStream_t stream) {
    const float* x  = (const float*)d_in[0];
    const int*   ei = (const int*)d_in[1];
    const float* W1 = (const float*)d_in[2];
    const float* b1 = (const float*)d_in[3];
    const float* W2 = (const float*)d_in[4];
    const float* b2 = (const float*)d_in[5];
    const float* W3 = (const float*)d_in[6];
    const float* b3 = (const float*)d_in[7];
    float* out = (float*)d_out;

    const int n = in_sizes[0] / N_HID;       // 100000
    const int E = in_sizes[1] / 2;           // 1600000
    const int total = E + n;

    const int* src = ei;
    const int* dst = ei + E;

    // ws layout
    size_t off = 0;
    auto alloc = [&](size_t bytes) {
        size_t o = off;
        off += (bytes + 255) & ~(size_t)255;
        return (char*)d_ws + o;
    };
    int*   deg    = (int*)  alloc((size_t)n * 4);
    float* dinv   = (float*)alloc((size_t)n * 4);
    int*   rptr   = (int*)  alloc((size_t)(n + 1) * 4);
    int*   cursor = (int*)  alloc((size_t)n * 4);
    int*   bsums  = (int*)  alloc(4096);
    int*   colx   = (int*)  alloc((size_t)(total + 3 * (size_t)n + 64) * 4);
    float* HH     = (float*)alloc((size_t)(n + 1) * N_HID * 4);  // +1 dummy zero row
    (void)ws_size;

    int nb  = (n + 255) / 256;               // 391
    int ebk = (E + 255) / 256;
    int tbk = (total + 255) / 256;

    k_init_deg<<<nb, 256, 0, stream>>>(deg, n);
    k_hist<<<ebk, 256, 0, stream>>>(dst, E, deg);
    k_dinv<<<nb, 256, 0, stream>>>(deg, dinv, n);
    k_scan1<<<nb, 256, 0, stream>>>(deg, rptr, bsums, n);
    k_scan2<<<1, 512, 0, stream>>>(bsums, nb);
    k_scan3<<<nb, 256, 0, stream>>>(rptr, bsums, deg, cursor, n);
    k_fill<<<tbk, 256, 0, stream>>>(src, dst, E, n, cursor, colx);
    k_pad<<<nb, 256, 0, stream>>>(rptr, deg, colx, n);
    k_zero_row<<<1, 128, 0, stream>>>(HH, n);

    int gblk = (n + 127) / 128;              // GEMM blocks
    int sblk = (n + 7) / 8;                  // SpMM blocks (8 half-waves/block)

    // layer 1: Hs = dinv * (x @ W1) ; out = relu(dinv*agg(Hs) + b1)
    k_gemm<<<gblk, 256, 0, stream>>>(x, W1, dinv, HH, n);
    k_spmm<<<sblk, 256, 0, stream>>>(HH, colx, rptr, dinv, b1, out, n, 1);
    // layer 2
    k_gemm<<<gblk, 256, 0, stream>>>(out, W2, dinv, HH, n);
    k_spmm<<<sblk, 256, 0, stream>>>(HH, colx, rptr, dinv, b2, out, n, 1);
    // layer 3 (no relu)
    k_gemm<<<gblk, 256, 0, stream>>>(out, W3, dinv, HH, n);
    k_spmm<<<sblk, 256, 0, stream>>>(HH, colx, rptr, dinv, b3, out, n, 0);
}

// Round 3
// 599.614 us; speedup vs baseline: 1.3599x; 1.2186x over previous
//
#include <hip/hip_runtime.h>
#include <hip/hip_bf16.h>

#define N_HID 128
#define BSH 9
#define BNODES 512          // nodes per bucket (1 << BSH)
#define CAP 14848           // LDS colx staging cap per bucket (58 KB)
#define CHUNK 4096          // edges per k_bucket block

// ---------------- bucketed CSR build ----------------

__global__ void k_zero_i(int* p, int m) {
    int i = blockIdx.x * 256 + threadIdx.x;
    if (i < m) p[i] = 0;
}

// count edges per dst-bucket (LDS-privatized)
__global__ __launch_bounds__(256) void k_bcount(const int* __restrict__ dst,
                                                int E, int n, int* __restrict__ gcount) {
    __shared__ int hist[256];
    int t = threadIdx.x;
    hist[t] = 0;
    __syncthreads();
    long base = (long)blockIdx.x * CHUNK;
    long T = (long)E + n;
    int cnt = (int)min((long)CHUNK, T - base);
    for (int j = t; j < cnt; j += 256) {
        long i = base + j;
        int d = (i < E) ? dst[i] : (int)(i - E);
        atomicAdd(&hist[d >> BSH], 1);
    }
    __syncthreads();
    if (hist[t] > 0) atomicAdd(&gcount[t], hist[t]);
}

// exclusive scan of bucket counts -> gbase0, init gcur
__global__ void k_bscan(const int* __restrict__ gcount, int* __restrict__ gbase0,
                        int* __restrict__ gcur, int nbk) {
    __shared__ int s[256];
    int t = threadIdx.x;
    int v = (t < nbk) ? gcount[t] : 0;
    s[t] = v;
    __syncthreads();
    for (int off = 1; off < 256; off <<= 1) {
        int y = (t >= off) ? s[t - off] : 0;
        __syncthreads();
        s[t] += y;
        __syncthreads();
    }
    if (t < nbk) { gbase0[t] = s[t] - v; gcur[t] = s[t] - v; }
}

// partition (src,dst) pairs into bucket-contiguous bpair[] with LDS reorder
__global__ __launch_bounds__(256) void k_bucket(const int* __restrict__ src,
                                                const int* __restrict__ dst,
                                                int E, int n, int* __restrict__ gcur,
                                                unsigned long long* __restrict__ bpair) {
    __shared__ int hist[256];
    __shared__ int incl[256];
    __shared__ int loff[256];
    __shared__ int gb[256];
    __shared__ unsigned long long lp[CHUNK];
    __shared__ unsigned char pb[CHUNK];
    int t = threadIdx.x;
    hist[t] = 0;
    __syncthreads();
    long base = (long)blockIdx.x * CHUNK;
    long T = (long)E + n;
    int cnt = (int)min((long)CHUNK, T - base);

    int s_[16], d_[16], r_[16];
    #pragma unroll
    for (int u = 0; u < 16; ++u) {
        int j = t + u * 256;
        if (j < cnt) {
            long i = base + j;
            int s, d;
            if (i < E) { s = src[i]; d = dst[i]; } else { s = (int)(i - E); d = s; }
            s_[u] = s; d_[u] = d;
            r_[u] = atomicAdd(&hist[d >> BSH], 1);
        } else { s_[u] = 0; d_[u] = 0; r_[u] = -1; }
    }
    __syncthreads();
    incl[t] = hist[t];
    __syncthreads();
    for (int off = 1; off < 256; off <<= 1) {
        int y = (t >= off) ? incl[t - off] : 0;
        __syncthreads();
        incl[t] += y;
        __syncthreads();
    }
    loff[t] = incl[t] - hist[t];
    if (hist[t] > 0) gb[t] = atomicAdd(&gcur[t], hist[t]);
    __syncthreads();
    #pragma unroll
    for (int u = 0; u < 16; ++u) {
        if (r_[u] >= 0) {
            int b = d_[u] >> BSH;
            int p = loff[b] + r_[u];
            lp[p] = ((unsigned long long)(unsigned)s_[u] << 32) | (unsigned)d_[u];
            pb[p] = (unsigned char)b;
        }
    }
    __syncthreads();
    for (int p = t; p < cnt; p += 256) {
        int b = pb[p];
        bpair[(size_t)gb[b] + (p - loff[b])] = lp[p];
    }
}

// per-bucket degree via LDS histogram (self-loops already in bpair)
__global__ __launch_bounds__(256) void k_bdeg(const unsigned long long* __restrict__ bpair,
                                              const int* __restrict__ gbase0,
                                              const int* __restrict__ gcount,
                                              int* __restrict__ deg, int n) {
    __shared__ int hist[BNODES];
    int b = blockIdx.x, t = threadIdx.x;
    for (int q = t; q < BNODES; q += 256) hist[q] = 0;
    __syncthreads();
    int gs = gbase0[b], ge = gs + gcount[b];
    int first = b << BSH;
    for (int e = gs + t; e < ge; e += 256) {
        int d = (int)(unsigned)(bpair[e] & 0xffffffffull);
        atomicAdd(&hist[d - first], 1);
    }
    __syncthreads();
    for (int q = t; q < BNODES; q += 256) {
        int node = first + q;
        if (node < n) deg[node] = hist[q];
    }
}

__global__ void k_dinv(const int* __restrict__ deg, float* __restrict__ dinv, int n) {
    int i = blockIdx.x * 256 + threadIdx.x;
    if (i < n) dinv[i] = rsqrtf((float)deg[i]);
}

// scan of PADDED degree (rounded up to multiple of 4)
__global__ void k_scan1(const int* __restrict__ deg, int* __restrict__ rptr,
                        int* __restrict__ bsums, int n) {
    __shared__ int s[256];
    int t = threadIdx.x;
    int i = blockIdx.x * 256 + t;
    int v = (i < n) ? ((deg[i] + 3) & ~3) : 0;
    s[t] = v;
    __syncthreads();
    for (int off = 1; off < 256; off <<= 1) {
        int y = (t >= off) ? s[t - off] : 0;
        __syncthreads();
        s[t] += y;
        __syncthreads();
    }
    if (i < n) rptr[i] = s[t] - v;
    if (t == 255) bsums[blockIdx.x] = s[255];
}

__global__ void k_scan2(int* bsums, int nb) {
    __shared__ int s[512];
    int t = threadIdx.x;
    int v = (t < nb) ? bsums[t] : 0;
    s[t] = v;
    __syncthreads();
    for (int off = 1; off < 512; off <<= 1) {
        int y = (t >= off) ? s[t - off] : 0;
        __syncthreads();
        s[t] += y;
        __syncthreads();
    }
    if (t < nb) bsums[t] = s[t] - v;
}

__global__ void k_scan3(int* __restrict__ rptr, const int* __restrict__ bsums,
                        const int* __restrict__ deg, int n) {
    int i = blockIdx.x * 256 + threadIdx.x;
    if (i < n) {
        int v = rptr[i] + bsums[blockIdx.x];
        rptr[i] = v;
        if (i == n - 1) rptr[n] = v + ((deg[i] + 3) & ~3);
    }
}

// per-bucket CSR fill: LDS scatter, pad with dummy node n, linear coalesced write
__global__ __launch_bounds__(256) void k_bfill(const unsigned long long* __restrict__ bpair,
                                               const int* __restrict__ gbase0,
                                               const int* __restrict__ gcount,
                                               const int* __restrict__ rptr,
                                               int* __restrict__ colx, int n) {
    __shared__ int cur[BNODES];
    __shared__ int lcol[CAP];
    int b = blockIdx.x, t = threadIdx.x;
    int first = b << BSH;
    int lastn = min(first + BNODES, n);
    int base = rptr[first];
    int tot = min(rptr[lastn] - base, CAP);
    for (int q = t; q < BNODES; q += 256) {
        int node = first + q;
        cur[q] = (node < lastn) ? (rptr[node] - base) : 0;
    }
    for (int p = t; p < tot; p += 256) lcol[p] = n;
    __syncthreads();
    int gs = gbase0[b], ge = gs + gcount[b];
    for (int e = gs + t; e < ge; e += 256) {
        unsigned long long pr = bpair[e];
        int d = (int)(unsigned)(pr & 0xffffffffull);
        int s = (int)(unsigned)(pr >> 32);
        int lpos = atomicAdd(&cur[d - first], 1);
        if (lpos < CAP) lcol[lpos] = s;
    }
    __syncthreads();
    for (int p = t; p < tot; p += 256) colx[base + p] = lcol[p];
}

__global__ void k_zero_row(float* Hs, int n) {
    Hs[(size_t)n * N_HID + threadIdx.x] = 0.f;
}

// ---------------- dense GEMM: Hs[M x 128] = scale[.] * (A[M x 128] @ W[128 x 128]) --------

__global__ __launch_bounds__(256) void k_gemm(const float* __restrict__ A,
                                              const float* __restrict__ W,
                                              const float* __restrict__ scale,
                                              float* __restrict__ C, int M) {
    __shared__ float As[32][132];
    __shared__ float Ws[32 * 128];   // repacked: [kk][h(2)][tx(16)][j(4)]
    int tid = threadIdx.x;
    int tx = tid & 15;
    int ty = tid >> 4;
    int bm = blockIdx.x * 128;
    float acc[8][8] = {};

    for (int k0 = 0; k0 < 128; k0 += 32) {
        #pragma unroll
        for (int it = 0; it < 4; ++it) {
            int idx = it * 256 + tid;
            int row = idx >> 3;
            int kq  = idx & 7;
            int grow = bm + row;
            float4 v = make_float4(0.f, 0.f, 0.f, 0.f);
            if (grow < M) v = *(const float4*)(A + (size_t)grow * 128 + k0 + kq * 4);
            As[kq * 4 + 0][row] = v.x;
            As[kq * 4 + 1][row] = v.y;
            As[kq * 4 + 2][row] = v.z;
            As[kq * 4 + 3][row] = v.w;
        }
        #pragma unroll
        for (int it = 0; it < 4; ++it) {
            int idx = it * 256 + tid;
            int kk = idx >> 5;
            int q  = idx & 31;
            float4 v = *(const float4*)(W + (size_t)(k0 + kk) * 128 + q * 4);
            *(float4*)&Ws[kk * 128 + ((q & 1) << 6) + ((q >> 1) << 2)] = v;
        }
        __syncthreads();
        #pragma unroll
        for (int kk = 0; kk < 32; ++kk) {
            float a[8], w[8];
            *(float4*)&a[0] = *(const float4*)&As[kk][ty * 8];
            *(float4*)&a[4] = *(const float4*)&As[kk][ty * 8 + 4];
            *(float4*)&w[0] = *(const float4*)&Ws[kk * 128 + tx * 4];
            *(float4*)&w[4] = *(const float4*)&Ws[kk * 128 + 64 + tx * 4];
            #pragma unroll
            for (int i = 0; i < 8; ++i)
                #pragma unroll
                for (int j = 0; j < 8; ++j)
                    acc[i][j] = fmaf(a[i], w[j], acc[i][j]);
        }
        __syncthreads();
    }
    #pragma unroll
    for (int i = 0; i < 8; ++i) {
        int grow = bm + ty * 8 + i;
        if (grow < M) {
            float di = scale[grow];
            float4 o0, o1;
            o0.x = acc[i][0] * di; o0.y = acc[i][1] * di;
            o0.z = acc[i][2] * di; o0.w = acc[i][3] * di;
            o1.x = acc[i][4] * di; o1.y = acc[i][5] * di;
            o1.z = acc[i][6] * di; o1.w = acc[i][7] * di;
            *(float4*)(C + (size_t)grow * 128 + tx * 8)     = o0;
            *(float4*)(C + (size_t)grow * 128 + tx * 8 + 4) = o1;
        }
    }
}

// ---------------- SpMM aggregate ----------------

__global__ __launch_bounds__(256) void k_spmm(const float* __restrict__ Hs,
                                              const int* __restrict__ colx,
                                              const int* __restrict__ rptr,
                                              const float* __restrict__ dinv,
                                              const float* __restrict__ bias,
                                              float* __restrict__ out,
                                              int n, int do_relu) {
    int node = blockIdx.x * 8 + (threadIdx.x >> 5);
    int lane = threadIdx.x & 31;
    if (node >= n) return;
    int e  = rptr[node];
    int e1 = rptr[node + 1];
    const int c = lane * 4;
    float4 acc = make_float4(0.f, 0.f, 0.f, 0.f);
    #pragma unroll 2
    for (; e < e1; e += 4) {
        int4 s = *(const int4*)(colx + e);
        float4 h0 = *(const float4*)(Hs + (size_t)s.x * 128 + c);
        float4 h1 = *(const float4*)(Hs + (size_t)s.y * 128 + c);
        float4 h2 = *(const float4*)(Hs + (size_t)s.z * 128 + c);
        float4 h3 = *(const float4*)(Hs + (size_t)s.w * 128 + c);
        acc.x += (h0.x + h1.x) + (h2.x + h3.x);
        acc.y += (h0.y + h1.y) + (h2.y + h3.y);
        acc.z += (h0.z + h1.z) + (h2.z + h3.z);
        acc.w += (h0.w + h1.w) + (h2.w + h3.w);
    }
    float di = dinv[node];
    float4 b = *(const float4*)(bias + c);
    float4 o;
    o.x = fmaf(di, acc.x, b.x);
    o.y = fmaf(di, acc.y, b.y);
    o.z = fmaf(di, acc.z, b.z);
    o.w = fmaf(di, acc.w, b.w);
    if (do_relu) {
        o.x = fmaxf(o.x, 0.f); o.y = fmaxf(o.y, 0.f);
        o.z = fmaxf(o.z, 0.f); o.w = fmaxf(o.w, 0.f);
    }
    *(float4*)(out + (size_t)node * 128 + c) = o;
}

// ---------------- host ----------------

extern "C" void kernel_launch(void* const* d_in, const int* in_sizes, int n_in,
                              void* d_out, int out_size, void* d_ws, size_t ws_size,
                              hipStream_t stream) {
    const float* x  = (const float*)d_in[0];
    const int*   ei = (const int*)d_in[1];
    const float* W1 = (const float*)d_in[2];
    const float* b1 = (const float*)d_in[3];
    const float* W2 = (const float*)d_in[4];
    const float* b2 = (const float*)d_in[5];
    const float* W3 = (const float*)d_in[6];
    const float* b3 = (const float*)d_in[7];
    float* out = (float*)d_out;

    const int n = in_sizes[0] / N_HID;       // 100000
    const int E = in_sizes[1] / 2;           // 1600000
    const long T = (long)E + n;

    const int* src = ei;
    const int* dst = ei + E;

    size_t off = 0;
    auto alloc = [&](size_t bytes) {
        size_t o = off;
        off += (bytes + 255) & ~(size_t)255;
        return (char*)d_ws + o;
    };
    int*   deg    = (int*)  alloc((size_t)n * 4);
    float* dinv   = (float*)alloc((size_t)n * 4);
    int*   rptr   = (int*)  alloc((size_t)(n + 1) * 4);
    int*   bsums  = (int*)  alloc(4096);
    int*   gcount = (int*)  alloc(1024);
    int*   gbase0 = (int*)  alloc(1024);
    int*   gcur   = (int*)  alloc(1024);
    int*   colx   = (int*)  alloc((size_t)(T + 3 * (size_t)n + 64) * 4);
    float* HH     = (float*)alloc((size_t)(n + 1) * N_HID * 4);  // +1 dummy zero row
    // bpair aliases HH's front 13.6 MB (consumed before first GEMM writes HH)
    unsigned long long* bpair = (unsigned long long*)HH;
    (void)ws_size;

    const int NBK  = (n + BNODES - 1) >> BSH;          // 196 buckets
    const int ABLK = (int)((T + CHUNK - 1) / CHUNK);   // 416 chunks
    const int nb   = (n + 255) / 256;                  // 391

    k_zero_i<<<1, 256, 0, stream>>>(gcount, NBK);
    k_bcount<<<ABLK, 256, 0, stream>>>(dst, E, n, gcount);
    k_bscan<<<1, 256, 0, stream>>>(gcount, gbase0, gcur, NBK);
    k_bucket<<<ABLK, 256, 0, stream>>>(src, dst, E, n, gcur, bpair);
    k_bdeg<<<NBK, 256, 0, stream>>>(bpair, gbase0, gcount, deg, n);
    k_dinv<<<nb, 256, 0, stream>>>(deg, dinv, n);
    k_scan1<<<nb, 256, 0, stream>>>(deg, rptr, bsums, n);
    k_scan2<<<1, 512, 0, stream>>>(bsums, nb);
    k_scan3<<<nb, 256, 0, stream>>>(rptr, bsums, deg, n);
    k_bfill<<<NBK, 256, 0, stream>>>(bpair, gbase0, gcount, rptr, colx, n);
    k_zero_row<<<1, 128, 0, stream>>>(HH, n);

    int gblk = (n + 127) / 128;
    int sblk = (n + 7) / 8;

    k_gemm<<<gblk, 256, 0, stream>>>(x, W1, dinv, HH, n);
    k_spmm<<<sblk, 256, 0, stream>>>(HH, colx, rptr, dinv, b1, out, n, 1);
    k_gemm<<<gblk, 256, 0, stream>>>(out, W2, dinv, HH, n);
    k_spmm<<<sblk, 256, 0, stream>>>(HH, colx, rptr, dinv, b2, out, n, 1);
    k_gemm<<<gblk, 256, 0, stream>>>(out, W3, dinv, HH, n);
    k_spmm<<<sblk, 256, 0, stream>>>(HH, colx, rptr, dinv, b3, out, n, 0);
}